// Round 6
// baseline (187.458 us; speedup 1.0000x reference)
//
#include <hip/hip_runtime.h>

typedef __attribute__((ext_vector_type(8))) short short8;
typedef __attribute__((ext_vector_type(4))) unsigned short ushort4v;
typedef __attribute__((ext_vector_type(4))) int int4v;
typedef __attribute__((ext_vector_type(4))) float f32x4;

#define Mdim 64
#define Kdim 8192
#define Ndim 8192
#define GRP 128
#define NGRP 64
#define KSPLIT 8
#define NG2 (NGRP / KSPLIT)   // 8 groups per block

__device__ __forceinline__ unsigned short f2bf(float f) {
    unsigned int u = __builtin_bit_cast(unsigned int, f);
    u += 0x7FFFu + ((u >> 16) & 1u);   // round-to-nearest-even
    return (unsigned short)(u >> 16);
}
__device__ __forceinline__ float bf2f(unsigned short h) {
    unsigned int u = ((unsigned int)h) << 16;
    return __builtin_bit_cast(float, u);
}

// Build xh/xl (hi/lo bf16 split of x) and per-(group,m) sums xsum[g][m].
__global__ void prep_kernel(const float* __restrict__ x,
                            unsigned short* __restrict__ xh,
                            unsigned short* __restrict__ xl,
                            float* __restrict__ xsum) {
    const int tid = threadIdx.x;
    const int u = blockIdx.x * 8 + (tid >> 5);
    const int g = u & (NGRP - 1);
    const int m = u >> 6;
    const int lane = tid & 31;
    const int k = g * GRP + lane * 4;
    f32x4 v = *(const f32x4*)(x + (size_t)m * Kdim + k);
    ushort4v hv, lv;
    float s = 0.f;
#pragma unroll
    for (int i = 0; i < 4; ++i) {
        unsigned short h = f2bf(v[i]);
        hv[i] = h;
        lv[i] = f2bf(v[i] - bf2f(h));
        s += v[i];
    }
    *(ushort4v*)(xh + (size_t)m * Kdim + k) = hv;
    *(ushort4v*)(xl + (size_t)m * Kdim + k) = lv;
#pragma unroll
    for (int off = 16; off > 0; off >>= 1) s += __shfl_down(s, off, 32);
    if (lane == 0) xsum[g * Mdim + m] = s;
}

// Main: 4096 blocks = 512 n-strips x 8 k-splits (kh in LSB -> per-XCD x slice
// stays L2-resident). ONE wave per block, private 16-col strip, private 4 KB
// LDS q-buffer (single-buffered; wave-internal ds ordering). NO barriers.
// Load order per group: hot loads (ds/s/z/x-mf0) BEFORE LOADQ(g+1) so the
// compiler's counted vmcnt leaves the 8 q HBM loads in flight under the MFMAs.
__launch_bounds__(64, 4)
__global__ void qlin_kernel(const unsigned short* __restrict__ xh,
                            const unsigned short* __restrict__ xl,
                            const int* __restrict__ qw,
                            const float* __restrict__ scales,
                            const float* __restrict__ zeros,
                            const float* __restrict__ xsum,
                            float* __restrict__ pout) {
    __shared__ unsigned short lq[16 * 128];   // [col16][k128] bf16, XOR-16B swizzled

    const int l = threadIdx.x;
    const int kh = blockIdx.x & (KSPLIT - 1);
    const int nw = (blockIdx.x >> 3) * 16;    // this wave's col base
    const int g0 = kh * NG2;

    const int lcol = l & 15;      // MFMA col / A-row lane
    const int lhi = l >> 4;       // 0..3
    const int kq = l >> 2;        // staging: k-octet 0..15
    const int cq = l & 3;         // staging: col-quad 0..3

    int4v qv[8];                  // staging regs: 8 k-rows x 4 cols of int q

    auto LOADQ = [&](int g) {     // g relative to g0
        const size_t kb = (size_t)(g0 + g) * GRP + kq * 8;
        const int nc = nw + cq * 4;
#pragma unroll
        for (int j = 0; j < 8; ++j)
            qv[j] = __builtin_nontemporal_load((const int4v*)(qw + (kb + j) * Ndim + nc));
    };
    auto WRITEQ = [&]() {         // exact int->bf16 (truncate; |q|<=128), b128 swizzled writes
#pragma unroll
        for (int i = 0; i < 4; ++i) {
            int4v pk;
#pragma unroll
            for (int t = 0; t < 4; ++t) {
                unsigned lo = __builtin_bit_cast(unsigned, (float)qv[2 * t][i]) >> 16;
                unsigned hi = __builtin_bit_cast(unsigned, (float)qv[2 * t + 1][i]) & 0xFFFF0000u;
                pk[t] = (int)(lo | hi);
            }
            const int r = cq * 4 + i;
            *(int4v*)&lq[r * 128 + ((8 * kq) ^ ((r & 7) << 3))] = pk;
        }
    };

    f32x4 acc[4];
#pragma unroll
    for (int mf = 0; mf < 4; ++mf) acc[mf] = {0.f, 0.f, 0.f, 0.f};

    LOADQ(0);
    WRITEQ();

    for (int g = 0; g < NG2; ++g) {
        const size_t ka = (size_t)(g0 + g) * GRP + lhi * 8;

        // 1. B-frags for group g from private LDS (staged last iter)
        short8 bq[4];
#pragma unroll
        for (int ks = 0; ks < 4; ++ks)
            bq[ks] = *(const short8*)&lq[lcol * 128 + ((ks * 32 + lhi * 8) ^ ((lcol & 7) << 3))];

        // 2. cheap hot loads for this group, BEFORE the q prefetch
        const float s = scales[(size_t)(g0 + g) * Ndim + nw + lcol];
        const float z = zeros[(size_t)(g0 + g) * Ndim + nw + lcol];

        // 3. x frags for mf=0, then 4. q prefetch (stays in flight under MFMAs)
        short8 ah[4], al[4];
        {
            const size_t xoff = (size_t)lcol * Kdim + ka;
#pragma unroll
            for (int ks = 0; ks < 4; ++ks) {
                ah[ks] = *(const short8*)(xh + xoff + ks * 32);
                al[ks] = *(const short8*)(xl + xoff + ks * 32);
            }
        }
        if (g + 1 < NG2) LOADQ(g + 1);

        // 5. MFMA + fold, mf = 0 then 1..3 (their x loads issue after q; fine)
#pragma unroll
        for (int mf = 0; mf < 4; ++mf) {
            if (mf > 0) {
                const size_t xoff = (size_t)(mf * 16 + lcol) * Kdim + ka;
#pragma unroll
                for (int ks = 0; ks < 4; ++ks) {
                    ah[ks] = *(const short8*)(xh + xoff + ks * 32);
                    al[ks] = *(const short8*)(xl + xoff + ks * 32);
                }
            }
            f32x4 p = {0.f, 0.f, 0.f, 0.f};
#pragma unroll
            for (int ks = 0; ks < 4; ++ks) {
                p = __builtin_amdgcn_mfma_f32_16x16x32_bf16(ah[ks], bq[ks], p, 0, 0, 0);
                p = __builtin_amdgcn_mfma_f32_16x16x32_bf16(al[ks], bq[ks], p, 0, 0, 0);
            }
            f32x4 xs = *(const f32x4*)(xsum + (g0 + g) * Mdim + mf * 16 + lhi * 4);
#pragma unroll
            for (int r = 0; r < 4; ++r)
                acc[mf][r] += s * (p[r] - z * xs[r]);
        }

        // 6. stage next group's q (waits its vmcnt; long since returned)
        if (g + 1 < NG2) WRITEQ();
    }

    const size_t ob = (size_t)kh * Mdim * Ndim;
#pragma unroll
    for (int mf = 0; mf < 4; ++mf)
#pragma unroll
        for (int r = 0; r < 4; ++r)
            pout[ob + (size_t)(mf * 16 + lhi * 4 + r) * Ndim + nw + lcol] = acc[mf][r];
}

// out = sum of KSPLIT partials + bias
__global__ void reduce_kernel(const float* __restrict__ pout,
                              const float* __restrict__ bias,
                              float* __restrict__ out) {
    const size_t e = ((size_t)blockIdx.x * 256 + threadIdx.x) * 4;
    const int n = (int)(e & (Ndim - 1));
    f32x4 a = *(const f32x4*)(bias + n);
#pragma unroll
    for (int s = 0; s < KSPLIT; ++s) {
        f32x4 ppart = *(const f32x4*)(pout + (size_t)s * Mdim * Ndim + e);
#pragma unroll
        for (int r = 0; r < 4; ++r) a[r] += ppart[r];
    }
    *(f32x4*)(out + e) = a;
}

extern "C" void kernel_launch(void* const* d_in, const int* in_sizes, int n_in,
                              void* d_out, int out_size, void* d_ws, size_t ws_size,
                              hipStream_t stream) {
    const float* x = (const float*)d_in[0];
    const int* qw = (const int*)d_in[1];
    const float* scales = (const float*)d_in[2];
    const float* zeros = (const float*)d_in[3];
    const float* bias = (const float*)d_in[4];

    unsigned short* xh = (unsigned short*)d_ws;
    unsigned short* xl = xh + (size_t)Mdim * Kdim;
    float* xsum = (float*)(xl + (size_t)Mdim * Kdim);
    float* pout = xsum + NGRP * Mdim;
    float* out = (float*)d_out;

    prep_kernel<<<512, 256, 0, stream>>>(x, xh, xl, xsum);
    qlin_kernel<<<(Ndim / 16) * KSPLIT, 64, 0, stream>>>(xh, xl, qw, scales, zeros, xsum, pout);
    reduce_kernel<<<(Mdim * Ndim / 4) / 256, 256, 0, stream>>>(pout, bias, out);
}

// Round 7
// 66.154 us; speedup vs baseline: 2.8336x; 2.8336x over previous
//
#include <hip/hip_runtime.h>

typedef __attribute__((ext_vector_type(8))) short short8;
typedef __attribute__((ext_vector_type(8))) unsigned short ushort8;
typedef __attribute__((ext_vector_type(4))) unsigned short ushort4v;
typedef __attribute__((ext_vector_type(4))) int int4v;
typedef __attribute__((ext_vector_type(4))) float f32x4;

#define Mdim 64
#define Kdim 8192
#define Ndim 8192
#define GRP 128
#define NGRP 64
#define KSPLIT 4
#define NG2 (NGRP / KSPLIT)   // 16 groups per block
#define BN 128

// Swizzled element offset in a [row][128]-bf16 LDS tile (256 B rows).
// kk is the k-element offset (multiple of 8 for all our 16B accesses).
// Verified conflict-free for: q-write (row=4qc+i,kk=8qr), x-write (row=xm,kk=8xc),
// B-frag read (row=n_local,kk=32ks+8lhi), A-frag read (row=m,kk=32ks+8lhi).
#define SWZ(row, kk) ((row)*128 + ((kk) ^ (8*((((row) >> 3) ^ (row)) & 7))))

__device__ __forceinline__ unsigned short f2bf(float f) {
    unsigned int u = __builtin_bit_cast(unsigned int, f);
    u += 0x7FFFu + ((u >> 16) & 1u);   // round-to-nearest-even
    return (unsigned short)(u >> 16);
}
__device__ __forceinline__ float bf2f(unsigned short h) {
    unsigned int u = ((unsigned int)h) << 16;
    return __builtin_bit_cast(float, u);
}

// Build xh/xl (hi/lo bf16 split of x) and per-(group,m) sums xsum[g][m].
__global__ void prep_kernel(const float* __restrict__ x,
                            unsigned short* __restrict__ xh,
                            unsigned short* __restrict__ xl,
                            float* __restrict__ xsum) {
    const int tid = threadIdx.x;
    const int u = blockIdx.x * 8 + (tid >> 5);
    const int g = u & (NGRP - 1);
    const int m = u >> 6;
    const int lane = tid & 31;
    const int k = g * GRP + lane * 4;
    f32x4 v = *(const f32x4*)(x + (size_t)m * Kdim + k);
    ushort4v hv, lv;
    float s = 0.f;
#pragma unroll
    for (int i = 0; i < 4; ++i) {
        unsigned short h = f2bf(v[i]);
        hv[i] = h;
        lv[i] = f2bf(v[i] - bf2f(h));
        s += v[i];
    }
    *(ushort4v*)(xh + (size_t)m * Kdim + k) = hv;
    *(ushort4v*)(xl + (size_t)m * Kdim + k) = lv;
#pragma unroll
    for (int off = 16; off > 0; off >>= 1) s += __shfl_down(s, off, 32);
    if (lane == 0) xsum[g * Mdim + m] = s;
}

// Main: 256 blocks = 64 n-tiles (BN=128) x KSPLIT=4 (kh in low bits -> each
// XCD hosts one kh cohort; x k-slice L2-resident). 512 threads = 8 waves,
// wave = 64m x 16n (4 m-frags). q double-buffered LDS (2x32 KB), x single-
// buffered (32 KB). Per k-row each block reads 512 B contiguous; lockstep
// barriers keep the 64-block cohort reading the same rows -> DRAM-friendly.
// vmcnt discipline: all global loads issued BEFORE compute (x before q);
// MFMA phase is lgkm-only; q drained only at WRITEQ, ~2000 cy after issue.
__launch_bounds__(512)
__global__ void qlin_kernel(const unsigned short* __restrict__ xh,
                            const unsigned short* __restrict__ xl,
                            const int* __restrict__ qw,
                            const float* __restrict__ scales,
                            const float* __restrict__ zeros,
                            const float* __restrict__ xsum,
                            float* __restrict__ pout) {
    __shared__ unsigned short lq[2][128 * 128];   // [buf][SWZ(n,k)] 32 KB each
    __shared__ unsigned short lxh[64 * 128];      // [SWZ(m,k)] 16 KB
    __shared__ unsigned short lxl[64 * 128];      // 16 KB

    const int tid = threadIdx.x;
    const int kh = blockIdx.x & (KSPLIT - 1);
    const int n0 = (blockIdx.x >> 2) * BN;
    const int g0 = kh * NG2;

    const int w = tid >> 6;       // wave 0..7 -> n-strip
    const int l = tid & 63;
    const int lcol = l & 15;
    const int lhi = l >> 4;

    // q staging: thread covers rows qr*8..+7, 16B col-chunk qc
    const int qc = tid & 31;
    const int qr = tid >> 5;
    // x staging: rows xm, xm+32; 8-elem chunk xc
    const int xc = tid & 15;
    const int xm = tid >> 4;

    const int nn = n0 + w * 16 + lcol;   // this lane's output column

    int4v qv[8];
    ushort8 xga, xgb, xgc, xgd;
    float s_n, z_n, s_c, z_c;
    f32x4 xs_n[4], xs_c[4];

    auto LOAD_SZX = [&](int g) {
        s_n = scales[(size_t)g * Ndim + nn];
        z_n = zeros[(size_t)g * Ndim + nn];
#pragma unroll
        for (int mf = 0; mf < 4; ++mf)
            xs_n[mf] = *(const f32x4*)(xsum + g * Mdim + mf * 16 + lhi * 4);
    };
    auto LOADX = [&](int g) {
        const size_t kb = (size_t)g * GRP + xc * 8;
        xga = *(const ushort8*)(xh + (size_t)xm * Kdim + kb);
        xgb = *(const ushort8*)(xh + (size_t)(xm + 32) * Kdim + kb);
        xgc = *(const ushort8*)(xl + (size_t)xm * Kdim + kb);
        xgd = *(const ushort8*)(xl + (size_t)(xm + 32) * Kdim + kb);
    };
    auto LOADQ = [&](int g) {
        const size_t kb = (size_t)g * GRP + qr * 8;
        const int nc = n0 + qc * 4;
#pragma unroll
        for (int j = 0; j < 8; ++j)
            qv[j] = *(const int4v*)(qw + (kb + j) * Ndim + nc);
    };
    auto WRITEX = [&]() {
        *(ushort8*)&lxh[SWZ(xm, xc * 8)] = xga;
        *(ushort8*)&lxh[SWZ(xm + 32, xc * 8)] = xgb;
        *(ushort8*)&lxl[SWZ(xm, xc * 8)] = xgc;
        *(ushort8*)&lxl[SWZ(xm + 32, xc * 8)] = xgd;
    };
    auto WRITEQ = [&](int bb) {   // exact int->bf16 (|q|<=128 => truncation exact)
#pragma unroll
        for (int i = 0; i < 4; ++i) {
            int4v pk;
#pragma unroll
            for (int t = 0; t < 4; ++t) {
                unsigned lo = __builtin_bit_cast(unsigned, (float)qv[2 * t][i]) >> 16;
                unsigned hi = __builtin_bit_cast(unsigned, (float)qv[2 * t + 1][i]) & 0xFFFF0000u;
                pk[t] = (int)(lo | hi);
            }
            *(int4v*)&lq[bb][SWZ(qc * 4 + i, qr * 8)] = pk;
        }
    };

    f32x4 acc[4];
#pragma unroll
    for (int mf = 0; mf < 4; ++mf) acc[mf] = {0.f, 0.f, 0.f, 0.f};

    // prologue: stage group g0
    LOAD_SZX(g0);
    LOADX(g0);
    LOADQ(g0);
    s_c = s_n; z_c = z_n;
#pragma unroll
    for (int mf = 0; mf < 4; ++mf) xs_c[mf] = xs_n[mf];
    WRITEX();
    WRITEQ(0);
    __syncthreads();

    for (int g = 0; g < NG2; ++g) {
        const int bb = g & 1;
        const bool more = (g + 1 < NG2);

        // prefetch issue for g+1: cheap vmem first, then x, then q (q youngest)
        if (more) {
            LOAD_SZX(g0 + g + 1);
            LOADX(g0 + g + 1);
            LOADQ(g0 + g + 1);
        }

        // compute phase: lgkm-only (no vmem waits -> q stays in flight)
        short8 bq[4];
#pragma unroll
        for (int ks = 0; ks < 4; ++ks)
            bq[ks] = *(const short8*)&lq[bb][SWZ(w * 16 + lcol, ks * 32 + lhi * 8)];
#pragma unroll
        for (int mf = 0; mf < 4; ++mf) {
            short8 ah[4], al[4];
#pragma unroll
            for (int ks = 0; ks < 4; ++ks) {
                ah[ks] = *(const short8*)&lxh[SWZ(mf * 16 + lcol, ks * 32 + lhi * 8)];
                al[ks] = *(const short8*)&lxl[SWZ(mf * 16 + lcol, ks * 32 + lhi * 8)];
            }
            f32x4 p = {0.f, 0.f, 0.f, 0.f};
#pragma unroll
            for (int ks = 0; ks < 4; ++ks) {
                p = __builtin_amdgcn_mfma_f32_16x16x32_bf16(ah[ks], bq[ks], p, 0, 0, 0);
                p = __builtin_amdgcn_mfma_f32_16x16x32_bf16(al[ks], bq[ks], p, 0, 0, 0);
            }
#pragma unroll
            for (int r = 0; r < 4; ++r)
                acc[mf][r] += s_c * (p[r] - z_c * xs_c[mf][r]);
        }

        if (more) {
            __syncthreads();              // all reads of x-buf and lq[bb] done
            s_c = s_n; z_c = z_n;         // waits vmcnt(12): s/z/xs landed
#pragma unroll
            for (int mf = 0; mf < 4; ++mf) xs_c[mf] = xs_n[mf];
            WRITEX();                     // waits vmcnt(8): x landed, q in flight
            WRITEQ(bb ^ 1);               // waits vmcnt(0): q, issued ~2k cy ago
            __syncthreads();              // staging visible for next iter
        }
    }

    const size_t ob = (size_t)kh * Mdim * Ndim;
#pragma unroll
    for (int mf = 0; mf < 4; ++mf)
#pragma unroll
        for (int r = 0; r < 4; ++r)
            pout[ob + (size_t)(mf * 16 + lhi * 4 + r) * Ndim + nn] = acc[mf][r];
}

// out = sum of KSPLIT partials + bias
__global__ void reduce_kernel(const float* __restrict__ pout,
                              const float* __restrict__ bias,
                              float* __restrict__ out) {
    const size_t e = ((size_t)blockIdx.x * 256 + threadIdx.x) * 4;
    const int n = (int)(e & (Ndim - 1));
    f32x4 a = *(const f32x4*)(bias + n);
#pragma unroll
    for (int s = 0; s < KSPLIT; ++s) {
        f32x4 ppart = *(const f32x4*)(pout + (size_t)s * Mdim * Ndim + e);
#pragma unroll
        for (int r = 0; r < 4; ++r) a[r] += ppart[r];
    }
    *(f32x4*)(out + e) = a;
}

extern "C" void kernel_launch(void* const* d_in, const int* in_sizes, int n_in,
                              void* d_out, int out_size, void* d_ws, size_t ws_size,
                              hipStream_t stream) {
    const float* x = (const float*)d_in[0];
    const int* qw = (const int*)d_in[1];
    const float* scales = (const float*)d_in[2];
    const float* zeros = (const float*)d_in[3];
    const float* bias = (const float*)d_in[4];

    unsigned short* xh = (unsigned short*)d_ws;
    unsigned short* xl = xh + (size_t)Mdim * Kdim;
    float* xsum = (float*)(xl + (size_t)Mdim * Kdim);
    float* pout = xsum + NGRP * Mdim;
    float* out = (float*)d_out;

    prep_kernel<<<512, 256, 0, stream>>>(x, xh, xl, xsum);
    qlin_kernel<<<(Ndim / BN) * KSPLIT, 512, 0, stream>>>(xh, xl, qw, scales, zeros, xsum, pout);
    reduce_kernel<<<(Mdim * Ndim / 4) / 256, 256, 0, stream>>>(pout, bias, out);
}